// Round 2
// baseline (1700.110 us; speedup 1.0000x reference)
//
#include <hip/hip_runtime.h>
#include <hip/hip_bf16.h>
#include <cstdint>

typedef unsigned short u16;
typedef __attribute__((ext_vector_type(8))) short short8;
typedef __attribute__((ext_vector_type(4))) float floatx4;

#define PA_TOTAL 13696   // sum of per-level pixel counts, each padded to 128
#define CCH 256
#define KTOT 2304        // 9 taps * 256 ic

struct Tables {
  int H[5], W[5], P[5], base[5], tile0[5];
  int lb[5], bb[5], cb[5];   // d_out offsets: logits, bbox, centerness per level
};
struct FeatPtrs { const float* f[5]; };

__device__ __forceinline__ u16 f2bf(float f) {
  union { float f; unsigned u; } v; v.f = f;
  unsigned r = v.u + 0x7fffu + ((v.u >> 16) & 1u);   // RNE
  return (u16)(r >> 16);
}

__device__ __forceinline__ void gl2lds16(const u16* g, u16* l) {
  __builtin_amdgcn_global_load_lds((const __attribute__((address_space(1))) unsigned int*)g,
                                   (__attribute__((address_space(3))) unsigned int*)l, 16, 0, 0);
}

// ---- weight reorder: [row][256 ic][3][3] f32 -> [row][9 tap][256 ic] bf16
__global__ void reorder_w(const float* __restrict__ w, u16* __restrict__ out, int n) {
  int idx = blockIdx.x * 256 + threadIdx.x;
  if (idx >= n) return;
  int k = idx % KTOT;
  int row = idx / KTOT;
  int tap = k >> 8, ic = k & 255;
  out[idx] = f2bf(w[(size_t)row * KTOT + ic * 9 + tap]);
}

// cls_pred (20 rows) + ctr_pred (1 row) combined into 21-row weight matrix
__global__ void reorder_pred_cls(const float* __restrict__ cls_w, const float* __restrict__ ctr_w,
                                 u16* __restrict__ out) {
  int idx = blockIdx.x * 256 + threadIdx.x;   // grid covers exactly 21*2304
  int k = idx % KTOT;
  int row = idx / KTOT;
  int tap = k >> 8, ic = k & 255;
  float v = (row < 20) ? cls_w[(size_t)row * KTOT + ic * 9 + tap] : ctr_w[ic * 9 + tap];
  out[idx] = f2bf(v);
}

// ---- inputs NCHW f32 -> NHWC bf16 at aligned per-level offsets
__global__ void convert_inputs(FeatPtrs fp, u16* __restrict__ out, Tables tb) {
  int idx = blockIdx.x * 256 + threadIdx.x;   // (b*256+c)*PA + p ; coalesced reads
  int p = idx % PA_TOTAL;
  int bc = idx / PA_TOTAL;
  int c = bc & 255, b = bc >> 8;
  int lvl = 0;
#pragma unroll
  for (int i = 1; i < 5; ++i) if (p >= tb.base[i]) lvl = i;
  int pl = p - tb.base[lvl];
  if (pl >= tb.P[lvl]) return;
  float v = fp.f[lvl][((size_t)b * CCH + c) * tb.P[lvl] + pl];
  out[((size_t)b * PA_TOTAL + p) * CCH + c] = f2bf(v);
}

// ---- implicit-GEMM conv3x3 SAME, bf16 MFMA 16x16x32, 128x128 tile, m97-style staging.
// X: NHWC bf16 [b][PA][256]. Wt: [Mrows][2304] bf16 (k = tap*256+ic).
// mode 0: write f32 NHWC to outF (tower stage)
// mode 1: cls+ctr pred -> d_out NCHW (oc<20 logits + bias, oc==20 ctr + bias2)
// mode 2: box pred -> d_out NCHW, exp((v+bias)*scale[lvl])
__global__ __launch_bounds__(256) void conv_mfma(
    const u16* __restrict__ X, const u16* __restrict__ Wt, const u16* __restrict__ zbuf,
    float* __restrict__ outF, float* __restrict__ dout,
    const float* __restrict__ bias, const float* __restrict__ bias2,
    const float* __restrict__ scales, Tables tb, int mode)
{
  const int t = blockIdx.x, b = blockIdx.y, mt = blockIdx.z;
  int lvl = 0;
#pragma unroll
  for (int i = 1; i < 5; ++i) if (t >= tb.tile0[i]) lvl = i;
  const int H = tb.H[lvl], W = tb.W[lvl], P = tb.P[lvl], base = tb.base[lvl];
  const int n0 = (t - tb.tile0[lvl]) * 128;

  const int tid = threadIdx.x;
  const int lane = tid & 63, wv = tid >> 6;
  const int wm = wv >> 1, wn = wv & 1;

  __shared__ u16 ldsX[128 * 32];   // [px][ic] 8KB
  __shared__ u16 ldsW[128 * 32];   // [oc][k]  8KB

  // staging: 512 16B-chunks per tile; thread handles chunk e=tid and e=tid+256
  const int q = tid & 3;           // 16B quarter within a 64B row
  const int px0 = tid >> 2;        // row (pixel or oc) 0..63
  const int px1 = px0 + 64;
  const int p0 = n0 + px0, p1 = n0 + px1;
  const int r0 = p0 / W, c0 = p0 - r0 * W;
  const int r1 = p1 / W, c1 = p1 - r1 * W;

  const u16* Xb = X + ((size_t)b * PA_TOTAL + base) * CCH;
  const u16* Wb0 = Wt + (size_t)(mt * 128 + px0) * KTOT + q * 8;
  const u16* Wb1 = Wt + (size_t)(mt * 128 + px1) * KTOT + q * 8;

  u16* ldsXd0 = ldsX + wv * 512;          // wave-uniform LDS dests (lane*16B added by HW)
  u16* ldsXd1 = ldsX + 2048 + wv * 512;
  u16* ldsWd0 = ldsW + wv * 512;
  u16* ldsWd1 = ldsW + 2048 + wv * 512;

  floatx4 acc[4][4];
#pragma unroll
  for (int i = 0; i < 4; ++i)
#pragma unroll
    for (int j = 0; j < 4; ++j) acc[i][j] = (floatx4)0.f;

  const int arow = lane & 15, k8 = (lane >> 4) * 8;

  for (int tap = 0; tap < 9; ++tap) {
    const int dh = tap / 3 - 1, dw = tap % 3 - 1;
    const bool v0 = ((unsigned)(r0 + dh) < (unsigned)H) & ((unsigned)(c0 + dw) < (unsigned)W);
    const bool v1 = ((unsigned)(r1 + dh) < (unsigned)H) & ((unsigned)(c1 + dw) < (unsigned)W);
    const u16* xb0 = v0 ? (Xb + (size_t)(p0 + dh * W + dw) * CCH + q * 8) : zbuf;
    const u16* xb1 = v1 ? (Xb + (size_t)(p1 + dh * W + dw) * CCH + q * 8) : zbuf;
    const u16* wb0 = Wb0 + tap * 256;
    const u16* wb1 = Wb1 + tap * 256;
    for (int icb = 0; icb < 8; ++icb) {
      __syncthreads();
      gl2lds16(xb0 + icb * 32, ldsXd0);
      gl2lds16(xb1 + icb * 32, ldsXd1);
      gl2lds16(wb0 + icb * 32, ldsWd0);
      gl2lds16(wb1 + icb * 32, ldsWd1);
      __syncthreads();
      short8 af[4], bfr[4];
#pragma unroll
      for (int i = 0; i < 4; ++i) af[i] = *(const short8*)(ldsW + (wm * 64 + i * 16 + arow) * 32 + k8);
#pragma unroll
      for (int j = 0; j < 4; ++j) bfr[j] = *(const short8*)(ldsX + (wn * 64 + j * 16 + arow) * 32 + k8);
#pragma unroll
      for (int i = 0; i < 4; ++i)
#pragma unroll
        for (int j = 0; j < 4; ++j)
          acc[i][j] = __builtin_amdgcn_mfma_f32_16x16x32_bf16(af[i], bfr[j], acc[i][j], 0, 0, 0);
    }
  }

  // epilogue; D[m=(lane>>4)*4+r][n=lane&15]
  if (mode == 0) {
#pragma unroll
    for (int j = 0; j < 4; ++j) {
      int pl = n0 + wn * 64 + j * 16 + (lane & 15);
      if (pl < P) {
        float* dst = outF + ((size_t)b * PA_TOTAL + base + pl) * CCH + mt * 128 + wm * 64 + (lane >> 4) * 4;
#pragma unroll
        for (int i = 0; i < 4; ++i) *(floatx4*)(dst + i * 16) = acc[i][j];
      }
    }
  } else if (mode == 1) {
#pragma unroll
    for (int j = 0; j < 4; ++j) {
      int pl = n0 + wn * 64 + j * 16 + (lane & 15);
      if (pl >= P) continue;
#pragma unroll
      for (int i = 0; i < 4; ++i) {
        int ocb = wm * 64 + i * 16 + (lane >> 4) * 4;
#pragma unroll
        for (int r = 0; r < 4; ++r) {
          int oc = ocb + r;
          float v = acc[i][j][r];
          if (oc < 20)       dout[tb.lb[lvl] + ((size_t)b * 20 + oc) * P + pl] = v + bias[oc];
          else if (oc == 20) dout[tb.cb[lvl] + (size_t)b * P + pl] = v + bias2[0];
        }
      }
    }
  } else {
    float sc = scales[lvl];
#pragma unroll
    for (int j = 0; j < 4; ++j) {
      int pl = n0 + wn * 64 + j * 16 + (lane & 15);
      if (pl >= P) continue;
#pragma unroll
      for (int i = 0; i < 4; ++i) {
        int ocb = wm * 64 + i * 16 + (lane >> 4) * 4;
#pragma unroll
        for (int r = 0; r < 4; ++r) {
          int oc = ocb + r;
          if (oc < 4) dout[tb.bb[lvl] + ((size_t)b * 4 + oc) * P + pl] = expf((acc[i][j][r] + bias[oc]) * sc);
        }
      }
    }
  }
}

// ---- GroupNorm: pass 1 reduce sum/sumsq per (b,lvl,group) via wave-reduce + atomics
__global__ void gn_reduce(const float* __restrict__ conv, float* __restrict__ stats, Tables tb) {
  int idx = blockIdx.x * 256 + threadIdx.x;  // (b*32+g)*PA + p  (wave-uniform b,g,lvl)
  int p = idx % PA_TOTAL;
  int bg = idx / PA_TOTAL;
  int g = bg & 31, b = bg >> 5;
  int lvl = 0;
#pragma unroll
  for (int i = 1; i < 5; ++i) if (p >= tb.base[i]) lvl = i;
  float s = 0.f, ss = 0.f;
  if (p - tb.base[lvl] < tb.P[lvl]) {
    const floatx4* src = (const floatx4*)(conv + ((size_t)b * PA_TOTAL + p) * CCH + g * 8);
    floatx4 a = src[0], c = src[1];
#pragma unroll
    for (int j = 0; j < 4; ++j) { s += a[j] + c[j]; ss += a[j] * a[j] + c[j] * c[j]; }
  }
#pragma unroll
  for (int off = 32; off; off >>= 1) { s += __shfl_down(s, off, 64); ss += __shfl_down(ss, off, 64); }
  if ((threadIdx.x & 63) == 0) {
    float* st = stats + ((b * 5 + lvl) * 32 + g) * 2;
    atomicAdd(st, s);
    atomicAdd(st + 1, ss);
  }
}

// ---- GroupNorm pass 2: normalize + affine + ReLU -> bf16 NHWC
__global__ void gn_norm(const float* __restrict__ conv, const float* __restrict__ stats,
                        const float* __restrict__ gamma, const float* __restrict__ beta,
                        u16* __restrict__ act, Tables tb) {
  int idx = blockIdx.x * 256 + threadIdx.x;
  int p = idx % PA_TOTAL;
  int bg = idx / PA_TOTAL;
  int g = bg & 31, b = bg >> 5;
  int lvl = 0;
#pragma unroll
  for (int i = 1; i < 5; ++i) if (p >= tb.base[i]) lvl = i;
  if (p - tb.base[lvl] >= tb.P[lvl]) return;
  const float* st = stats + ((b * 5 + lvl) * 32 + g) * 2;
  float cnt = 8.f * (float)tb.P[lvl];
  float mean = st[0] / cnt;
  float var = st[1] / cnt - mean * mean;
  float inv = rsqrtf(var + 1e-5f);
  const floatx4* src = (const floatx4*)(conv + ((size_t)b * PA_TOTAL + p) * CCH + g * 8);
  floatx4 a = src[0], c = src[1];
  short8 o;
#pragma unroll
  for (int j = 0; j < 8; ++j) {
    float x = (j < 4) ? a[j] : c[j - 4];
    float y = (x - mean) * inv * gamma[g * 8 + j] + beta[g * 8 + j];
    y = fmaxf(y, 0.f);
    o[j] = (short)f2bf(y);
  }
  *(short8*)(act + ((size_t)b * PA_TOTAL + p) * CCH + g * 8) = o;
}

extern "C" void kernel_launch(void* const* d_in, const int* in_sizes, int n_in,
                              void* d_out, int out_size, void* d_ws, size_t ws_size,
                              hipStream_t stream) {
  const float* feat[5];
  for (int i = 0; i < 5; ++i) feat[i] = (const float*)d_in[i];
  const float* cls_tw_w  = (const float*)d_in[5];
  const float* cls_tw_g  = (const float*)d_in[6];
  const float* cls_tw_b  = (const float*)d_in[7];
  const float* box_tw_w  = (const float*)d_in[8];
  const float* box_tw_g  = (const float*)d_in[9];
  const float* box_tw_b  = (const float*)d_in[10];
  const float* cls_pred_w = (const float*)d_in[11];
  const float* cls_pred_b = (const float*)d_in[12];
  const float* box_pred_w = (const float*)d_in[13];
  const float* box_pred_b = (const float*)d_in[14];
  const float* ctr_pred_w = (const float*)d_in[15];
  const float* ctr_pred_b = (const float*)d_in[16];
  const float* scales     = (const float*)d_in[17];
  float* out = (float*)d_out;

  char* ws = (char*)d_ws;
  u16*   zbuf   = (u16*)(ws);                        // 512 B zeros
  float* stats  = (float*)(ws + 512);                // 2560 B
  u16*   WrCls  = (u16*)(ws + 3072);                 // 4*256 x 2304 bf16
  u16*   WrBox  = (u16*)(ws + 3072 + 4718592);
  u16*   WrPCls = (u16*)(ws + 3072 + 2 * 4718592);   // 128 x 2304 bf16 (21 used)
  u16*   WrPBox = (u16*)(ws + 3072 + 2 * 4718592 + 589824);
  u16*   bufIn  = (u16*)(ws + 3072 + 2 * 4718592 + 2 * 589824);
  u16*   bufAct = (u16*)(ws + 3072 + 2 * 4718592 + 2 * 589824 + 14024704);
  float* bufConv = (float*)(ws + 3072 + 2 * 4718592 + 2 * 589824 + 2 * (size_t)14024704);

  Tables tb = { {100,50,25,13,7}, {100,50,25,13,7}, {10000,2500,625,169,49},
                {0,10112,12672,13312,13568}, {0,79,99,104,106},
                {0,400000,500000,525000,531760},
                {533720,613720,633720,638720,640072},
                {640464,660464,665464,666714,667052} };

  hipMemsetAsync(zbuf, 0, 512, stream);
  hipMemsetAsync(WrPCls, 0, 589824, stream);
  hipMemsetAsync(WrPBox, 0, 589824, stream);

  reorder_w<<<9216, 256, 0, stream>>>(cls_tw_w, WrCls, 1024 * KTOT);
  reorder_w<<<9216, 256, 0, stream>>>(box_tw_w, WrBox, 1024 * KTOT);
  reorder_pred_cls<<<189, 256, 0, stream>>>(cls_pred_w, ctr_pred_w, WrPCls);
  reorder_w<<<36, 256, 0, stream>>>(box_pred_w, WrPBox, 4 * KTOT);

  FeatPtrs fp = {{feat[0], feat[1], feat[2], feat[3], feat[4]}};
  convert_inputs<<<27392, 256, 0, stream>>>(fp, bufIn, tb);

  for (int tower = 0; tower < 2; ++tower) {
    const u16* Wr = tower ? WrBox : WrCls;
    const float* gm = tower ? box_tw_g : cls_tw_g;
    const float* bt = tower ? box_tw_b : cls_tw_b;
    for (int s = 0; s < 4; ++s) {
      const u16* src = (s == 0) ? bufIn : bufAct;
      conv_mfma<<<dim3(107, 2, 2), 256, 0, stream>>>(src, Wr + (size_t)s * 256 * KTOT, zbuf,
                                                     bufConv, nullptr, nullptr, nullptr, nullptr, tb, 0);
      hipMemsetAsync(stats, 0, 2560, stream);
      gn_reduce<<<3424, 256, 0, stream>>>(bufConv, stats, tb);
      gn_norm<<<3424, 256, 0, stream>>>(bufConv, stats, gm + s * 256, bt + s * 256, bufAct, tb);
    }
    if (tower == 0) {
      conv_mfma<<<dim3(107, 2, 1), 256, 0, stream>>>(bufAct, WrPCls, zbuf, nullptr, out,
                                                     cls_pred_b, ctr_pred_b, nullptr, tb, 1);
    } else {
      conv_mfma<<<dim3(107, 2, 1), 256, 0, stream>>>(bufAct, WrPBox, zbuf, nullptr, out,
                                                     box_pred_b, nullptr, scales, tb, 2);
    }
  }
}

// Round 3
// 1000.822 us; speedup vs baseline: 1.6987x; 1.6987x over previous
//
#include <hip/hip_runtime.h>
#include <hip/hip_bf16.h>
#include <cstdint>

typedef unsigned short u16;
typedef __attribute__((ext_vector_type(8))) short short8;
typedef __attribute__((ext_vector_type(4))) float floatx4;

#define PA_TOTAL 13696   // sum of per-level pixel counts, each padded to 128
#define CCH 256
#define KTOT 2304        // 9 taps * 256 ic

struct Tables {
  int H[5], W[5], P[5], base[5], tile0[5];
  int lb[5], bb[5], cb[5];   // d_out offsets: logits, bbox, centerness per level
};
struct FeatPtrs { const float* f[5]; };

__device__ __forceinline__ u16 f2bf(float f) {
  union { float f; unsigned u; } v; v.f = f;
  unsigned r = v.u + 0x7fffu + ((v.u >> 16) & 1u);   // RNE
  return (u16)(r >> 16);
}
__device__ __forceinline__ float bf2f(u16 h) {
  union { unsigned u; float f; } v; v.u = ((unsigned)h) << 16;
  return v.f;
}

__device__ __forceinline__ void gl2lds16(const u16* g, u16* l) {
  __builtin_amdgcn_global_load_lds((const __attribute__((address_space(1))) unsigned int*)g,
                                   (__attribute__((address_space(3))) unsigned int*)l, 16, 0, 0);
}

// ---- weight reorder: [row][256 ic][3][3] f32 -> [row][9 tap][256 ic] bf16
__global__ void reorder_w(const float* __restrict__ w, u16* __restrict__ out, int n) {
  int idx = blockIdx.x * 256 + threadIdx.x;
  if (idx >= n) return;
  int k = idx % KTOT;
  int row = idx / KTOT;
  int tap = k >> 8, ic = k & 255;
  out[idx] = f2bf(w[(size_t)row * KTOT + ic * 9 + tap]);
}

// cls_pred (20 rows) + ctr_pred (1 row) combined into 21-row weight matrix
__global__ void reorder_pred_cls(const float* __restrict__ cls_w, const float* __restrict__ ctr_w,
                                 u16* __restrict__ out) {
  int idx = blockIdx.x * 256 + threadIdx.x;   // grid covers exactly 21*2304
  int k = idx % KTOT;
  int row = idx / KTOT;
  int tap = k >> 8, ic = k & 255;
  float v = (row < 20) ? cls_w[(size_t)row * KTOT + ic * 9 + tap] : ctr_w[ic * 9 + tap];
  out[idx] = f2bf(v);
}

// ---- inputs NCHW f32 -> NHWC bf16 at aligned per-level offsets
__global__ void convert_inputs(FeatPtrs fp, u16* __restrict__ out, Tables tb) {
  int idx = blockIdx.x * 256 + threadIdx.x;   // (b*256+c)*PA + p ; coalesced reads
  int p = idx % PA_TOTAL;
  int bc = idx / PA_TOTAL;
  int c = bc & 255, b = bc >> 8;
  int lvl = 0;
#pragma unroll
  for (int i = 1; i < 5; ++i) if (p >= tb.base[i]) lvl = i;
  int pl = p - tb.base[lvl];
  if (pl >= tb.P[lvl]) return;
  float v = fp.f[lvl][((size_t)b * CCH + c) * tb.P[lvl] + pl];
  out[((size_t)b * PA_TOTAL + p) * CCH + c] = f2bf(v);
}

// ---- implicit-GEMM conv3x3 SAME, bf16 MFMA 16x16x32, 128x128 tile, m97-style staging.
// X: NHWC bf16 [b][PA][256]. Wt: [Mrows][2304] bf16 (k = tap*256+ic).
// mode 0: write bf16 NHWC to convB + fused GN stats (sum/sumsq per (b,lvl,group)) via atomics
// mode 1: cls+ctr pred -> d_out NCHW (oc<20 logits + bias, oc==20 ctr + bias2)
// mode 2: box pred -> d_out NCHW, exp((v+bias)*scale[lvl])
__global__ __launch_bounds__(256) void conv_mfma(
    const u16* __restrict__ X, const u16* __restrict__ Wt, const u16* __restrict__ zbuf,
    u16* __restrict__ convB, float* __restrict__ stats, float* __restrict__ dout,
    const float* __restrict__ bias, const float* __restrict__ bias2,
    const float* __restrict__ scales, Tables tb, int mode)
{
  const int t = blockIdx.x, b = blockIdx.y, mt = blockIdx.z;
  int lvl = 0;
#pragma unroll
  for (int i = 1; i < 5; ++i) if (t >= tb.tile0[i]) lvl = i;
  const int H = tb.H[lvl], W = tb.W[lvl], P = tb.P[lvl], base = tb.base[lvl];
  const int n0 = (t - tb.tile0[lvl]) * 128;

  const int tid = threadIdx.x;
  const int lane = tid & 63, wv = tid >> 6;
  const int wm = wv >> 1, wn = wv & 1;

  __shared__ u16 ldsX[128 * 32];   // [px][ic] 8KB
  __shared__ u16 ldsW[128 * 32];   // [oc][k]  8KB

  // staging: 512 16B-chunks per tile; thread handles chunk e=tid and e=tid+256
  const int q = tid & 3;           // 16B quarter within a 64B row
  const int px0 = tid >> 2;        // row (pixel or oc) 0..63
  const int px1 = px0 + 64;
  const int p0 = n0 + px0, p1 = n0 + px1;
  const int r0 = p0 / W, c0 = p0 - r0 * W;
  const int r1 = p1 / W, c1 = p1 - r1 * W;

  const u16* Xb = X + ((size_t)b * PA_TOTAL + base) * CCH;
  const u16* Wb0 = Wt + (size_t)(mt * 128 + px0) * KTOT + q * 8;
  const u16* Wb1 = Wt + (size_t)(mt * 128 + px1) * KTOT + q * 8;

  u16* ldsXd0 = ldsX + wv * 512;          // wave-uniform LDS dests (lane*16B added by HW)
  u16* ldsXd1 = ldsX + 2048 + wv * 512;
  u16* ldsWd0 = ldsW + wv * 512;
  u16* ldsWd1 = ldsW + 2048 + wv * 512;

  floatx4 acc[4][4];
#pragma unroll
  for (int i = 0; i < 4; ++i)
#pragma unroll
    for (int j = 0; j < 4; ++j) acc[i][j] = (floatx4)0.f;

  const int arow = lane & 15, k8 = (lane >> 4) * 8;

  for (int tap = 0; tap < 9; ++tap) {
    const int dh = tap / 3 - 1, dw = tap % 3 - 1;
    const bool v0 = ((unsigned)(r0 + dh) < (unsigned)H) & ((unsigned)(c0 + dw) < (unsigned)W);
    const bool v1 = ((unsigned)(r1 + dh) < (unsigned)H) & ((unsigned)(c1 + dw) < (unsigned)W);
    const u16* xb0 = v0 ? (Xb + (size_t)(p0 + dh * W + dw) * CCH + q * 8) : zbuf;
    const u16* xb1 = v1 ? (Xb + (size_t)(p1 + dh * W + dw) * CCH + q * 8) : zbuf;
    const u16* wb0 = Wb0 + tap * 256;
    const u16* wb1 = Wb1 + tap * 256;
    for (int icb = 0; icb < 8; ++icb) {
      __syncthreads();
      gl2lds16(xb0 + icb * 32, ldsXd0);
      gl2lds16(xb1 + icb * 32, ldsXd1);
      gl2lds16(wb0 + icb * 32, ldsWd0);
      gl2lds16(wb1 + icb * 32, ldsWd1);
      __syncthreads();
      short8 af[4], bfr[4];
#pragma unroll
      for (int i = 0; i < 4; ++i) af[i] = *(const short8*)(ldsW + (wm * 64 + i * 16 + arow) * 32 + k8);
#pragma unroll
      for (int j = 0; j < 4; ++j) bfr[j] = *(const short8*)(ldsX + (wn * 64 + j * 16 + arow) * 32 + k8);
#pragma unroll
      for (int i = 0; i < 4; ++i)
#pragma unroll
        for (int j = 0; j < 4; ++j)
          acc[i][j] = __builtin_amdgcn_mfma_f32_16x16x32_bf16(af[i], bfr[j], acc[i][j], 0, 0, 0);
    }
  }

  // epilogue; D[m=(lane>>4)*4+r][n=lane&15]
  const int quad = lane >> 4, col = lane & 15;
  if (mode == 0) {
    float s[4] = {0.f, 0.f, 0.f, 0.f}, ss[4] = {0.f, 0.f, 0.f, 0.f};
#pragma unroll
    for (int j = 0; j < 4; ++j) {
      int pl = n0 + wn * 64 + j * 16 + col;
      bool valid = pl < P;
      u16* dst = convB + ((size_t)b * PA_TOTAL + base + pl) * CCH + mt * 128 + wm * 64 + quad * 4;
#pragma unroll
      for (int i = 0; i < 4; ++i) {
        ushort4 h;
#pragma unroll
        for (int r = 0; r < 4; ++r) {
          u16 hh = f2bf(acc[i][j][r]);
          ((u16*)&h)[r] = hh;
          float vr = bf2f(hh);                    // accumulate the ROUNDED value -> GN self-consistent
          if (valid) { s[i] += vr; ss[i] += vr * vr; }
        }
        if (valid) *(ushort4*)(dst + i * 16) = h;  // 8B store
      }
    }
    // reduce within wave: lanes 0..31 (quads 0,1 -> group half 0), 32..63 (half 1)
#pragma unroll
    for (int i = 0; i < 4; ++i) {
#pragma unroll
      for (int off = 16; off >= 1; off >>= 1) {
        s[i] += __shfl_down(s[i], off, 64);
        ss[i] += __shfl_down(ss[i], off, 64);
      }
    }
    if ((lane & 31) == 0) {
      int half = lane >> 5;
#pragma unroll
      for (int i = 0; i < 4; ++i) {
        float* st = stats + ((size_t)((b * 5 + lvl) * 32 + mt * 16 + wm * 8 + i * 2 + half)) * 2;
        atomicAdd(st, s[i]);
        atomicAdd(st + 1, ss[i]);
      }
    }
  } else if (mode == 1) {
#pragma unroll
    for (int j = 0; j < 4; ++j) {
      int pl = n0 + wn * 64 + j * 16 + col;
      if (pl >= P) continue;
#pragma unroll
      for (int i = 0; i < 4; ++i) {
        int ocb = wm * 64 + i * 16 + quad * 4;
#pragma unroll
        for (int r = 0; r < 4; ++r) {
          int oc = ocb + r;
          float v = acc[i][j][r];
          if (oc < 20)       dout[tb.lb[lvl] + ((size_t)b * 20 + oc) * P + pl] = v + bias[oc];
          else if (oc == 20) dout[tb.cb[lvl] + (size_t)b * P + pl] = v + bias2[0];
        }
      }
    }
  } else {
    float sc = scales[lvl];
#pragma unroll
    for (int j = 0; j < 4; ++j) {
      int pl = n0 + wn * 64 + j * 16 + col;
      if (pl >= P) continue;
#pragma unroll
      for (int i = 0; i < 4; ++i) {
        int ocb = wm * 64 + i * 16 + quad * 4;
#pragma unroll
        for (int r = 0; r < 4; ++r) {
          int oc = ocb + r;
          if (oc < 4) dout[tb.bb[lvl] + ((size_t)b * 4 + oc) * P + pl] = expf((acc[i][j][r] + bias[oc]) * sc);
        }
      }
    }
  }
}

// ---- GroupNorm pass 2: normalize + affine + ReLU, bf16 -> bf16, fully coalesced.
// thread <-> (b, pixel, 8-channel chunk), chunk fastest: 16B contiguous per lane.
__global__ void gn_norm(const u16* __restrict__ convB, const float* __restrict__ stats,
                        const float* __restrict__ gamma, const float* __restrict__ beta,
                        u16* __restrict__ act, Tables tb) {
  int idx = blockIdx.x * 256 + threadIdx.x;
  int c8 = idx & 31;                 // == group index
  int rest = idx >> 5;
  int p = rest % PA_TOTAL;
  int b = rest / PA_TOTAL;
  int lvl = 0;
#pragma unroll
  for (int i = 1; i < 5; ++i) if (p >= tb.base[i]) lvl = i;
  if (p - tb.base[lvl] >= tb.P[lvl]) return;
  const float* st = stats + ((size_t)((b * 5 + lvl) * 32 + c8)) * 2;
  float cnt = 8.f * (float)tb.P[lvl];
  float mean = st[0] / cnt;
  float var = st[1] / cnt - mean * mean;
  float inv = rsqrtf(var + 1e-5f);
  const short8 x = *(const short8*)(convB + ((size_t)b * PA_TOTAL + p) * CCH + c8 * 8);
  short8 o;
#pragma unroll
  for (int j = 0; j < 8; ++j) {
    float v = bf2f((u16)x[j]);
    float y = (v - mean) * inv * gamma[c8 * 8 + j] + beta[c8 * 8 + j];
    y = fmaxf(y, 0.f);
    o[j] = (short)f2bf(y);
  }
  *(short8*)(act + ((size_t)b * PA_TOTAL + p) * CCH + c8 * 8) = o;
}

extern "C" void kernel_launch(void* const* d_in, const int* in_sizes, int n_in,
                              void* d_out, int out_size, void* d_ws, size_t ws_size,
                              hipStream_t stream) {
  const float* feat[5];
  for (int i = 0; i < 5; ++i) feat[i] = (const float*)d_in[i];
  const float* cls_tw_w  = (const float*)d_in[5];
  const float* cls_tw_g  = (const float*)d_in[6];
  const float* cls_tw_b  = (const float*)d_in[7];
  const float* box_tw_w  = (const float*)d_in[8];
  const float* box_tw_g  = (const float*)d_in[9];
  const float* box_tw_b  = (const float*)d_in[10];
  const float* cls_pred_w = (const float*)d_in[11];
  const float* cls_pred_b = (const float*)d_in[12];
  const float* box_pred_w = (const float*)d_in[13];
  const float* box_pred_b = (const float*)d_in[14];
  const float* ctr_pred_w = (const float*)d_in[15];
  const float* ctr_pred_b = (const float*)d_in[16];
  const float* scales     = (const float*)d_in[17];
  float* out = (float*)d_out;

  char* ws = (char*)d_ws;
  u16*   zbuf   = (u16*)(ws);                        // 512 B zeros
  float* stats  = (float*)(ws + 512);                // 2560 B
  u16*   WrCls  = (u16*)(ws + 3072);                 // 4*256 x 2304 bf16
  u16*   WrBox  = (u16*)(ws + 3072 + 4718592);
  u16*   WrPCls = (u16*)(ws + 3072 + 2 * 4718592);   // 128 x 2304 bf16 (21 used)
  u16*   WrPBox = (u16*)(ws + 3072 + 2 * 4718592 + 589824);
  u16*   bufIn  = (u16*)(ws + 3072 + 2 * 4718592 + 2 * 589824);
  u16*   bufAct = (u16*)(ws + 3072 + 2 * 4718592 + 2 * 589824 + 14024704);
  u16*   bufConv = (u16*)(ws + 3072 + 2 * 4718592 + 2 * 589824 + 2 * (size_t)14024704);

  Tables tb = { {100,50,25,13,7}, {100,50,25,13,7}, {10000,2500,625,169,49},
                {0,10112,12672,13312,13568}, {0,79,99,104,106},
                {0,400000,500000,525000,531760},
                {533720,613720,633720,638720,640072},
                {640464,660464,665464,666714,667052} };

  hipMemsetAsync(zbuf, 0, 512, stream);
  hipMemsetAsync(WrPCls, 0, 589824, stream);
  hipMemsetAsync(WrPBox, 0, 589824, stream);

  reorder_w<<<9216, 256, 0, stream>>>(cls_tw_w, WrCls, 1024 * KTOT);
  reorder_w<<<9216, 256, 0, stream>>>(box_tw_w, WrBox, 1024 * KTOT);
  reorder_pred_cls<<<189, 256, 0, stream>>>(cls_pred_w, ctr_pred_w, WrPCls);
  reorder_w<<<36, 256, 0, stream>>>(box_pred_w, WrPBox, 4 * KTOT);

  FeatPtrs fp = {{feat[0], feat[1], feat[2], feat[3], feat[4]}};
  convert_inputs<<<27392, 256, 0, stream>>>(fp, bufIn, tb);

  for (int tower = 0; tower < 2; ++tower) {
    const u16* Wr = tower ? WrBox : WrCls;
    const float* gm = tower ? box_tw_g : cls_tw_g;
    const float* bt = tower ? box_tw_b : cls_tw_b;
    for (int s = 0; s < 4; ++s) {
      const u16* src = (s == 0) ? bufIn : bufAct;
      hipMemsetAsync(stats, 0, 2560, stream);
      conv_mfma<<<dim3(107, 2, 2), 256, 0, stream>>>(src, Wr + (size_t)s * 256 * KTOT, zbuf,
                                                     bufConv, stats, nullptr, nullptr, nullptr, nullptr, tb, 0);
      gn_norm<<<3424, 256, 0, stream>>>(bufConv, stats, gm + s * 256, bt + s * 256, bufAct, tb);
    }
    if (tower == 0) {
      conv_mfma<<<dim3(107, 2, 1), 256, 0, stream>>>(bufAct, WrPCls, zbuf, nullptr, nullptr, out,
                                                     cls_pred_b, ctr_pred_b, nullptr, tb, 1);
    } else {
      conv_mfma<<<dim3(107, 2, 1), 256, 0, stream>>>(bufAct, WrPBox, zbuf, nullptr, nullptr, out,
                                                     box_pred_b, nullptr, scales, tb, 2);
    }
  }
}

// Round 5
// 764.138 us; speedup vs baseline: 2.2249x; 1.3097x over previous
//
#include <hip/hip_runtime.h>
#include <hip/hip_bf16.h>
#include <cstdint>

typedef unsigned short u16;
typedef __attribute__((ext_vector_type(8))) short short8;
typedef __attribute__((ext_vector_type(4))) float floatx4;

#define PA_TOTAL 13696   // sum of per-level pixel counts, each padded to 128
#define CCH 256
#define KTOT 2304        // 9 taps * 256 ic

struct Tables {
  int H[5], W[5], P[5], base[5], tile0[5];
  int lb[5], bb[5], cb[5];   // d_out offsets: logits, bbox, centerness per level
};
struct FeatPtrs { const float* f[5]; };
struct ConvArgs {
  const u16* X[2];      // per-tower input activations
  const u16* Wt[2];     // per-tower weight matrices for this stage
  const u16* zbuf;
  u16* outB[2];         // per-tower conv output (bf16 NHWC)
  float* stats;         // [tower][ (b*5+lvl)*32+g ][2]  -> tower stride 640 floats
  float* dout;
  const float* biasCls; const float* biasCtr; const float* biasBox; const float* scales;
};

__device__ __forceinline__ u16 f2bf(float f) {
  union { float f; unsigned u; } v; v.f = f;
  unsigned r = v.u + 0x7fffu + ((v.u >> 16) & 1u);   // RNE
  return (u16)(r >> 16);
}
__device__ __forceinline__ float bf2f(u16 h) {
  union { unsigned u; float f; } v; v.u = ((unsigned)h) << 16;
  return v.f;
}

__device__ __forceinline__ void gl2lds16(const u16* g, u16* l) {
  __builtin_amdgcn_global_load_lds((const __attribute__((address_space(1))) unsigned int*)g,
                                   (__attribute__((address_space(3))) unsigned int*)l, 16, 0, 0);
}

// ---- weight reorder: [row][256 ic][3][3] f32 -> [row][9 tap][256 ic] bf16
__global__ void reorder_w(const float* __restrict__ w, u16* __restrict__ out, int n) {
  int idx = blockIdx.x * 256 + threadIdx.x;
  if (idx >= n) return;
  int k = idx % KTOT;
  int row = idx / KTOT;
  int tap = k >> 8, ic = k & 255;
  out[idx] = f2bf(w[(size_t)row * KTOT + ic * 9 + tap]);
}

// cls_pred (20 rows) + ctr_pred (1 row) combined into 21-row weight matrix
__global__ void reorder_pred_cls(const float* __restrict__ cls_w, const float* __restrict__ ctr_w,
                                 u16* __restrict__ out) {
  int idx = blockIdx.x * 256 + threadIdx.x;   // grid covers exactly 21*2304
  int k = idx % KTOT;
  int row = idx / KTOT;
  int tap = k >> 8, ic = k & 255;
  float v = (row < 20) ? cls_w[(size_t)row * KTOT + ic * 9 + tap] : ctr_w[ic * 9 + tap];
  out[idx] = f2bf(v);
}

// ---- inputs NCHW f32 -> NHWC bf16, 32x32 LDS transpose (coalesced both sides)
// grid: (PA_TOTAL/32, 8, 2)  block 256
__global__ void convert_inputs(FeatPtrs fp, u16* __restrict__ out, Tables tb) {
  __shared__ float tile[32][33];
  const int pt = blockIdx.x, c32 = blockIdx.y, b = blockIdx.z;
  const int p0 = pt * 32;
  int lvl = 0;
#pragma unroll
  for (int i = 1; i < 5; ++i) if (p0 >= tb.base[i]) lvl = i;
  const int P = tb.P[lvl];
  const int pl0 = p0 - tb.base[lvl];
  const int r = threadIdx.x >> 5, col = threadIdx.x & 31;
  const float* src = fp.f[lvl] + ((size_t)b * CCH + c32 * 32) * P;
#pragma unroll
  for (int i = 0; i < 4; ++i) {
    int crow = r + i * 8;
    int pl = pl0 + col;
    tile[crow][col] = (pl < P) ? src[(size_t)crow * P + pl] : 0.f;
  }
  __syncthreads();
#pragma unroll
  for (int i = 0; i < 4; ++i) {
    int px = r + i * 8;
    out[((size_t)b * PA_TOTAL + p0 + px) * CCH + c32 * 32 + col] = f2bf(tile[col][px]);
  }
}

// ---- implicit-GEMM conv3x3 SAME, bf16 MFMA 16x16x32, 128x128 tile, BK=64,
// XOR-swizzled LDS (conflict-free ds_read_b128), towers merged in one dispatch.
// MODE 0: tower stage -> bf16 NHWC + fused GN stats. z = tower*2 + mt.
// MODE 1: pred convs -> d_out NCHW. z = tower (0: cls/ctr, 1: box-exp).
template <int MODE>
__global__ __launch_bounds__(256) void conv_mfma(ConvArgs a, Tables tb) {
  const int t = blockIdx.x, b = blockIdx.y, z = blockIdx.z;
  const int tower = (MODE == 0) ? (z >> 1) : z;
  const int mt = (MODE == 0) ? (z & 1) : 0;
  int lvl = 0;
#pragma unroll
  for (int i = 1; i < 5; ++i) if (t >= tb.tile0[i]) lvl = i;
  const int H = tb.H[lvl], W = tb.W[lvl], P = tb.P[lvl], base = tb.base[lvl];
  const int n0 = (t - tb.tile0[lvl]) * 128;

  const int tid = threadIdx.x;
  const int lane = tid & 63, wv = tid >> 6;
  const int wm = wv >> 1, wn = wv & 1;

  __shared__ u16 ldsX[128 * 64];   // [px][64 ic] swizzled, 16KB
  __shared__ u16 ldsW[128 * 64];   // [oc][64 k]  swizzled, 16KB

  const u16* X = a.X[tower];
  const u16* Wt = a.Wt[tower];
  const u16* zbuf = a.zbuf;

  // staging: 1024 16B-chunks per tile; thread handles 4 (pass t4=0..3).
  // chunk ci = (t4*4+wv)*64 + lane -> row = ci>>3, col = ci&7.
  // slot (row,col) holds k-chunk q' = col ^ (row&7); q' is a per-thread constant.
  const int qsw = (((lane & 7) ^ (lane >> 3))) * 8;   // u16 offset of fetched chunk
  int prow[4], rr[4], cc[4];
  const u16* wsrc[4];
  u16 *ldsXd[4], *ldsWd[4];
#pragma unroll
  for (int t4 = 0; t4 < 4; ++t4) {
    int row = (t4 * 4 + wv) * 8 + (lane >> 3);
    prow[t4] = n0 + row;
    rr[t4] = prow[t4] / W; cc[t4] = prow[t4] - rr[t4] * W;
    wsrc[t4] = Wt + (size_t)(mt * 128 + row) * KTOT + qsw;
    ldsXd[t4] = ldsX + (t4 * 4 + wv) * 512;   // wave-uniform base
    ldsWd[t4] = ldsW + (t4 * 4 + wv) * 512;
  }
  const u16* Xbp = X + ((size_t)b * PA_TOTAL + base) * CCH;

  // loop-invariant fragment LDS offsets (u16), reader swizzle col = kq ^ (row&7)
  const int arow = lane & 15, rsw = lane & 7, kq0 = lane >> 4;
  int aoff[2][4], boff[2][4];
#pragma unroll
  for (int h = 0; h < 2; ++h) {
    int csw = (((h * 4 + kq0) ^ rsw)) * 8;
#pragma unroll
    for (int i = 0; i < 4; ++i) {
      aoff[h][i] = (wm * 64 + i * 16 + arow) * 64 + csw;
      boff[h][i] = (wn * 64 + i * 16 + arow) * 64 + csw;
    }
  }

  floatx4 acc[4][4];
#pragma unroll
  for (int i = 0; i < 4; ++i)
#pragma unroll
    for (int j = 0; j < 4; ++j) acc[i][j] = (floatx4)0.f;

  for (int tap = 0; tap < 9; ++tap) {
    const int dh = tap / 3 - 1, dw = tap % 3 - 1;
    const u16* xof[4];
#pragma unroll
    for (int t4 = 0; t4 < 4; ++t4) {
      bool v = ((unsigned)(rr[t4] + dh) < (unsigned)H) & ((unsigned)(cc[t4] + dw) < (unsigned)W);
      xof[t4] = v ? (Xbp + (size_t)(prow[t4] + dh * W + dw) * CCH + qsw) : nullptr;
    }
#pragma unroll 1
    for (int icb = 0; icb < 4; ++icb) {
      const int ko = tap * 256 + icb * 64;
      __syncthreads();
#pragma unroll
      for (int t4 = 0; t4 < 4; ++t4) gl2lds16(xof[t4] ? xof[t4] + icb * 64 : zbuf, ldsXd[t4]);
#pragma unroll
      for (int t4 = 0; t4 < 4; ++t4) gl2lds16(wsrc[t4] + ko, ldsWd[t4]);
      __syncthreads();
#pragma unroll
      for (int h = 0; h < 2; ++h) {
        short8 af[4], bv[4];
#pragma unroll
        for (int i = 0; i < 4; ++i) af[i] = *(const short8*)(ldsW + aoff[h][i]);
#pragma unroll
        for (int j = 0; j < 4; ++j) bv[j] = *(const short8*)(ldsX + boff[h][j]);
#pragma unroll
        for (int i = 0; i < 4; ++i)
#pragma unroll
          for (int j = 0; j < 4; ++j)
            acc[i][j] = __builtin_amdgcn_mfma_f32_16x16x32_bf16(af[i], bv[j], acc[i][j], 0, 0, 0);
      }
    }
  }

  // epilogue; D[m=(lane>>4)*4+r][n=lane&15]
  const int quad = lane >> 4, col = lane & 15;
  if (MODE == 0) {
    u16* convB = a.outB[tower];
    float s[4] = {0.f, 0.f, 0.f, 0.f}, ss[4] = {0.f, 0.f, 0.f, 0.f};
#pragma unroll
    for (int j = 0; j < 4; ++j) {
      int pl = n0 + wn * 64 + j * 16 + col;
      bool valid = pl < P;
      u16* dst = convB + ((size_t)b * PA_TOTAL + base + pl) * CCH + mt * 128 + wm * 64 + quad * 4;
#pragma unroll
      for (int i = 0; i < 4; ++i) {
        ushort4 hv;
#pragma unroll
        for (int r = 0; r < 4; ++r) {
          u16 hh = f2bf(acc[i][j][r]);
          ((u16*)&hv)[r] = hh;
          float vr = bf2f(hh);                    // accumulate ROUNDED value -> GN self-consistent
          if (valid) { s[i] += vr; ss[i] += vr * vr; }
        }
        if (valid) *(ushort4*)(dst + i * 16) = hv;
      }
    }
#pragma unroll
    for (int i = 0; i < 4; ++i) {
#pragma unroll
      for (int off = 16; off >= 1; off >>= 1) {
        s[i] += __shfl_down(s[i], off, 64);
        ss[i] += __shfl_down(ss[i], off, 64);
      }
    }
    if ((lane & 31) == 0) {
      int half = lane >> 5;
#pragma unroll
      for (int i = 0; i < 4; ++i) {
        float* st = a.stats + tower * 640 +
                    ((size_t)((b * 5 + lvl) * 32 + mt * 16 + wm * 8 + i * 2 + half)) * 2;
        atomicAdd(st, s[i]);
        atomicAdd(st + 1, ss[i]);
      }
    }
  } else {
    float* dout = a.dout;
    if (tower == 0) {
#pragma unroll
      for (int j = 0; j < 4; ++j) {
        int pl = n0 + wn * 64 + j * 16 + col;
        if (pl >= P) continue;
#pragma unroll
        for (int i = 0; i < 4; ++i) {
          int ocb = wm * 64 + i * 16 + quad * 4;
#pragma unroll
          for (int r = 0; r < 4; ++r) {
            int oc = ocb + r;
            float v = acc[i][j][r];
            if (oc < 20)       dout[tb.lb[lvl] + ((size_t)b * 20 + oc) * P + pl] = v + a.biasCls[oc];
            else if (oc == 20) dout[tb.cb[lvl] + (size_t)b * P + pl] = v + a.biasCtr[0];
          }
        }
      }
    } else {
      float sc = a.scales[lvl];
#pragma unroll
      for (int j = 0; j < 4; ++j) {
        int pl = n0 + wn * 64 + j * 16 + col;
        if (pl >= P) continue;
#pragma unroll
        for (int i = 0; i < 4; ++i) {
          int ocb = wm * 64 + i * 16 + quad * 4;
#pragma unroll
          for (int r = 0; r < 4; ++r) {
            int oc = ocb + r;
            if (oc < 4)
              dout[tb.bb[lvl] + ((size_t)b * 4 + oc) * P + pl] = expf((acc[i][j][r] + a.biasBox[oc]) * sc);
          }
        }
      }
    }
  }
}

// ---- GroupNorm pass 2: normalize + affine + ReLU, bf16 -> bf16, coalesced; both towers.
// grid (3424, 2): y = tower
__global__ void gn_norm(const u16* __restrict__ c0, const u16* __restrict__ c1,
                        const float* __restrict__ stats,
                        const float* __restrict__ g0, const float* __restrict__ b0,
                        const float* __restrict__ g1, const float* __restrict__ b1,
                        u16* __restrict__ a0, u16* __restrict__ a1, Tables tb) {
  const int tower = blockIdx.y;
  const u16* convB = tower ? c1 : c0;
  const float* gamma = tower ? g1 : g0;
  const float* beta = tower ? b1 : b0;
  u16* act = tower ? a1 : a0;
  int idx = blockIdx.x * 256 + threadIdx.x;
  int c8 = idx & 31;                 // == group index
  int rest = idx >> 5;
  int p = rest % PA_TOTAL;
  int b = rest / PA_TOTAL;
  int lvl = 0;
#pragma unroll
  for (int i = 1; i < 5; ++i) if (p >= tb.base[i]) lvl = i;
  if (p - tb.base[lvl] >= tb.P[lvl]) return;
  const float* st = stats + tower * 640 + ((size_t)((b * 5 + lvl) * 32 + c8)) * 2;
  float cnt = 8.f * (float)tb.P[lvl];
  float mean = st[0] / cnt;
  float var = st[1] / cnt - mean * mean;
  float inv = rsqrtf(var + 1e-5f);
  const short8 x = *(const short8*)(convB + ((size_t)b * PA_TOTAL + p) * CCH + c8 * 8);
  short8 o;
#pragma unroll
  for (int j = 0; j < 8; ++j) {
    float v = bf2f((u16)x[j]);
    float y = (v - mean) * inv * gamma[c8 * 8 + j] + beta[c8 * 8 + j];
    y = fmaxf(y, 0.f);
    o[j] = (short)f2bf(y);
  }
  *(short8*)(act + ((size_t)b * PA_TOTAL + p) * CCH + c8 * 8) = o;
}

extern "C" void kernel_launch(void* const* d_in, const int* in_sizes, int n_in,
                              void* d_out, int out_size, void* d_ws, size_t ws_size,
                              hipStream_t stream) {
  const float* feat[5];
  for (int i = 0; i < 5; ++i) feat[i] = (const float*)d_in[i];
  const float* cls_tw_w  = (const float*)d_in[5];
  const float* cls_tw_g  = (const float*)d_in[6];
  const float* cls_tw_b  = (const float*)d_in[7];
  const float* box_tw_w  = (const float*)d_in[8];
  const float* box_tw_g  = (const float*)d_in[9];
  const float* box_tw_b  = (const float*)d_in[10];
  const float* cls_pred_w = (const float*)d_in[11];
  const float* cls_pred_b = (const float*)d_in[12];
  const float* box_pred_w = (const float*)d_in[13];
  const float* box_pred_b = (const float*)d_in[14];
  const float* ctr_pred_w = (const float*)d_in[15];
  const float* ctr_pred_b = (const float*)d_in[16];
  const float* scales     = (const float*)d_in[17];
  float* out = (float*)d_out;

  char* ws = (char*)d_ws;
  u16*   zbuf   = (u16*)(ws);                        // 512 B zeros
  float* stats  = (float*)(ws + 512);                // 5120 B: [2 towers][320 groups][2]
  u16*   WrCls  = (u16*)(ws + 8192);                 // 1024 x 2304 bf16
  u16*   WrBox  = (u16*)(ws + 8192 + 4718592);
  u16*   WrPCls = (u16*)(ws + 8192 + 2 * 4718592);   // 128 x 2304 bf16 (21 used)
  u16*   WrPBox = (u16*)(ws + 8192 + 2 * 4718592 + 589824);
  u16*   bufIn   = (u16*)(ws + 10625024);
  u16*   bufAct0 = (u16*)(ws + 10625024 + 1 * (size_t)14024704);
  u16*   bufAct1 = (u16*)(ws + 10625024 + 2 * (size_t)14024704);
  u16*   bufCv0  = (u16*)(ws + 10625024 + 3 * (size_t)14024704);
  u16*   bufCv1  = (u16*)(ws + 10625024 + 4 * (size_t)14024704);

  Tables tb = { {100,50,25,13,7}, {100,50,25,13,7}, {10000,2500,625,169,49},
                {0,10112,12672,13312,13568}, {0,79,99,104,106},
                {0,400000,500000,525000,531760},
                {533720,613720,633720,638720,640072},
                {640464,660464,665464,666714,667052} };

  hipMemsetAsync(zbuf, 0, 512, stream);
  hipMemsetAsync(WrPCls, 0, 589824, stream);
  hipMemsetAsync(WrPBox, 0, 589824, stream);

  reorder_w<<<9216, 256, 0, stream>>>(cls_tw_w, WrCls, 1024 * KTOT);
  reorder_w<<<9216, 256, 0, stream>>>(box_tw_w, WrBox, 1024 * KTOT);
  reorder_pred_cls<<<189, 256, 0, stream>>>(cls_pred_w, ctr_pred_w, WrPCls);
  reorder_w<<<36, 256, 0, stream>>>(box_pred_w, WrPBox, 4 * KTOT);

  FeatPtrs fp = {{feat[0], feat[1], feat[2], feat[3], feat[4]}};
  convert_inputs<<<dim3(PA_TOTAL / 32, 8, 2), 256, 0, stream>>>(fp, bufIn, tb);

  ConvArgs a;
  a.zbuf = zbuf; a.stats = stats; a.dout = out;
  a.biasCls = cls_pred_b; a.biasCtr = ctr_pred_b; a.biasBox = box_pred_b; a.scales = scales;
  a.outB[0] = bufCv0; a.outB[1] = bufCv1;

  for (int s = 0; s < 4; ++s) {
    a.X[0] = (s == 0) ? bufIn : bufAct0;
    a.X[1] = (s == 0) ? bufIn : bufAct1;
    a.Wt[0] = WrCls + (size_t)s * 256 * KTOT;
    a.Wt[1] = WrBox + (size_t)s * 256 * KTOT;
    hipMemsetAsync(stats, 0, 5120, stream);
    conv_mfma<0><<<dim3(107, 2, 4), 256, 0, stream>>>(a, tb);
    gn_norm<<<dim3(3424, 2), 256, 0, stream>>>(bufCv0, bufCv1, stats,
                                               cls_tw_g + s * 256, cls_tw_b + s * 256,
                                               box_tw_g + s * 256, box_tw_b + s * 256,
                                               bufAct0, bufAct1, tb);
  }
  a.X[0] = bufAct0; a.X[1] = bufAct1;
  a.Wt[0] = WrPCls; a.Wt[1] = WrPBox;
  conv_mfma<1><<<dim3(107, 2, 2), 256, 0, stream>>>(a, tb);
}

// Round 7
// 670.409 us; speedup vs baseline: 2.5359x; 1.1398x over previous
//
#include <hip/hip_runtime.h>
#include <hip/hip_bf16.h>
#include <cstdint>

typedef unsigned short u16;
typedef __attribute__((ext_vector_type(8))) short short8;
typedef __attribute__((ext_vector_type(4))) float floatx4;

#define PA_TOTAL 13696   // sum of per-level pixel counts, each padded to 128
#define CCH 256
#define KTOT 2304        // 9 taps * 256 ic

struct Tables {
  int H[5], W[5], P[5], base[5], tile0[5];
  int lb[5], bb[5], cb[5];   // d_out offsets: logits, bbox, centerness per level
};
struct FeatPtrs { const float* f[5]; };
struct ConvArgs {
  const u16* X[2];      // per-tower input activations
  const u16* Wt[2];     // per-tower weight matrices for this stage
  const u16* zbuf;
  u16* outB[2];         // per-tower conv output (bf16 NHWC)
  float* stats;         // [tower][ (b*5+lvl)*32+g ][2]  -> tower stride 640 floats
  float* dout;
  const float* biasCls; const float* biasCtr; const float* biasBox; const float* scales;
};

__device__ __forceinline__ u16 f2bf(float f) {
  union { float f; unsigned u; } v; v.f = f;
  unsigned r = v.u + 0x7fffu + ((v.u >> 16) & 1u);   // RNE
  return (u16)(r >> 16);
}
__device__ __forceinline__ float bf2f(u16 h) {
  union { unsigned u; float f; } v; v.u = ((unsigned)h) << 16;
  return v.f;
}

__device__ __forceinline__ void gl2lds16(const u16* g, u16* l) {
  __builtin_amdgcn_global_load_lds((const __attribute__((address_space(1))) unsigned int*)g,
                                   (__attribute__((address_space(3))) unsigned int*)l, 16, 0, 0);
}

// ---- weight reorder: [row][256 ic][3][3] f32 -> [row][9 tap][256 ic] bf16
__global__ void reorder_w(const float* __restrict__ w, u16* __restrict__ out, int n) {
  int idx = blockIdx.x * 256 + threadIdx.x;
  if (idx >= n) return;
  int k = idx % KTOT;
  int row = idx / KTOT;
  int tap = k >> 8, ic = k & 255;
  out[idx] = f2bf(w[(size_t)row * KTOT + ic * 9 + tap]);
}

// cls_pred (20 rows) + ctr_pred (1 row) combined into 21-row weight matrix
__global__ void reorder_pred_cls(const float* __restrict__ cls_w, const float* __restrict__ ctr_w,
                                 u16* __restrict__ out) {
  int idx = blockIdx.x * 256 + threadIdx.x;   // grid covers exactly 21*2304
  int k = idx % KTOT;
  int row = idx / KTOT;
  int tap = k >> 8, ic = k & 255;
  float v = (row < 20) ? cls_w[(size_t)row * KTOT + ic * 9 + tap] : ctr_w[ic * 9 + tap];
  out[idx] = f2bf(v);
}

// ---- inputs NCHW f32 -> NHWC bf16, 32x32 LDS transpose (coalesced both sides)
// grid: (PA_TOTAL/32, 8, 2)  block 256
__global__ void convert_inputs(FeatPtrs fp, u16* __restrict__ out, Tables tb) {
  __shared__ float tile[32][33];
  const int pt = blockIdx.x, c32 = blockIdx.y, b = blockIdx.z;
  const int p0 = pt * 32;
  int lvl = 0;
#pragma unroll
  for (int i = 1; i < 5; ++i) if (p0 >= tb.base[i]) lvl = i;
  const int P = tb.P[lvl];
  const int pl0 = p0 - tb.base[lvl];
  const int r = threadIdx.x >> 5, col = threadIdx.x & 31;
  const float* src = fp.f[lvl] + ((size_t)b * CCH + c32 * 32) * P;
#pragma unroll
  for (int i = 0; i < 4; ++i) {
    int crow = r + i * 8;
    int pl = pl0 + col;
    tile[crow][col] = (pl < P) ? src[(size_t)crow * P + pl] : 0.f;
  }
  __syncthreads();
#pragma unroll
  for (int i = 0; i < 4; ++i) {
    int px = r + i * 8;
    out[((size_t)b * PA_TOTAL + p0 + px) * CCH + c32 * 32 + col] = f2bf(tile[col][px]);
  }
}

// ---- implicit-GEMM conv3x3 SAME, bf16 MFMA 16x16x32, 128x128 tile, BK=64,
// XOR-swizzled LDS (conflict-free ds_read_b128), towers merged in one dispatch.
// XCD-aware block permute: linear block id L -> XCD = L%8 (round-robin heuristic);
// each XCD owns one (z,b) slice so W-tile + X-input stay resident in its private L2.
// MODE 0: tower stage -> bf16 NHWC + fused GN stats. grid (107,2,4) = 856 = 107*8.
// MODE 1: pred convs -> d_out NCHW. grid (108,2,2) = 432 = 54*8 (4 blocks guard out).
template <int MODE>
__global__ __launch_bounds__(256) void conv_mfma(ConvArgs a, Tables tb) {
  const int L = blockIdx.x + (MODE == 0 ? 107 : 108) * (blockIdx.y + 2 * blockIdx.z);
  const int xcd = L & 7, slot = L >> 3;
  int tower, mt, b, t;
  if (MODE == 0) {
    // 856 blocks: slot = 0..106 for every xcd
    tower = xcd >> 2; mt = (xcd >> 1) & 1; b = xcd & 1; t = slot;
  } else {
    // 432 blocks: slot = 0..53 for every xcd; t = slot*2 + parity, guard t<107
    tower = xcd >> 2; mt = 0; b = (xcd >> 1) & 1; t = slot * 2 + (xcd & 1);
    if (t >= 107) return;
  }
  int lvl = 0;
#pragma unroll
  for (int i = 1; i < 5; ++i) if (t >= tb.tile0[i]) lvl = i;
  const int H = tb.H[lvl], W = tb.W[lvl], P = tb.P[lvl], base = tb.base[lvl];
  const int n0 = (t - tb.tile0[lvl]) * 128;

  const int tid = threadIdx.x;
  const int lane = tid & 63, wv = tid >> 6;
  const int wm = wv >> 1, wn = wv & 1;

  __shared__ u16 ldsX[128 * 64];   // [px][64 ic] swizzled, 16KB
  __shared__ u16 ldsW[128 * 64];   // [oc][64 k]  swizzled, 16KB

  const u16* X = a.X[tower];
  const u16* Wt = a.Wt[tower];
  const u16* zbuf = a.zbuf;

  // staging: 1024 16B-chunks per tile; thread handles 4 (pass t4=0..3).
  // chunk ci = (t4*4+wv)*64 + lane -> row = ci>>3, col = ci&7.
  // slot (row,col) holds k-chunk q' = col ^ (row&7); q' is a per-thread constant.
  const int qsw = (((lane & 7) ^ (lane >> 3))) * 8;   // u16 offset of fetched chunk
  int prow[4];
  unsigned mask9[4];                 // per-staging-row tap validity bits
  const u16* wsrc[4];
  u16 *ldsXd[4], *ldsWd[4];
#pragma unroll
  for (int t4 = 0; t4 < 4; ++t4) {
    int row = (t4 * 4 + wv) * 8 + (lane >> 3);
    prow[t4] = n0 + row;
    int rr = prow[t4] / W, cc = prow[t4] - rr * W;
    unsigned m = 0;
#pragma unroll
    for (int tap = 0; tap < 9; ++tap) {
      const int dh = tap / 3 - 1, dw = tap % 3 - 1;
      bool v = ((unsigned)(rr + dh) < (unsigned)H) & ((unsigned)(cc + dw) < (unsigned)W);
      m |= ((unsigned)v) << tap;
    }
    mask9[t4] = m;
    wsrc[t4] = Wt + (size_t)(mt * 128 + row) * KTOT + qsw;
    ldsXd[t4] = ldsX + (t4 * 4 + wv) * 512;   // wave-uniform base
    ldsWd[t4] = ldsW + (t4 * 4 + wv) * 512;
  }
  const u16* Xbp = X + ((size_t)b * PA_TOTAL + base) * CCH;

  // loop-invariant fragment LDS offsets (u16), reader swizzle col = kq ^ (row&7)
  const int arow = lane & 15, rsw = lane & 7, kq0 = lane >> 4;
  int aoff[2][4], boff[2][4];
#pragma unroll
  for (int h = 0; h < 2; ++h) {
    int csw = (((h * 4 + kq0) ^ rsw)) * 8;
#pragma unroll
    for (int i = 0; i < 4; ++i) {
      aoff[h][i] = (wm * 64 + i * 16 + arow) * 64 + csw;
      boff[h][i] = (wn * 64 + i * 16 + arow) * 64 + csw;
    }
  }

  floatx4 acc[4][4];
#pragma unroll
  for (int i = 0; i < 4; ++i)
#pragma unroll
    for (int j = 0; j < 4; ++j) acc[i][j] = (floatx4)0.f;

  // K-loop: icb outer, taps inner (unrolled) -> the 9 shifted X reads of the same
  // lines happen back-to-back (L1/L2 temporal locality), dpos folds to constants.
#pragma unroll 1
  for (int icb = 0; icb < 4; ++icb) {
#pragma unroll
    for (int tap = 0; tap < 9; ++tap) {
      const int dh = tap / 3 - 1, dw = tap % 3 - 1;
      const int dpos = dh * W + dw;
      const int ko = tap * 256 + icb * 64;
      __syncthreads();
#pragma unroll
      for (int t4 = 0; t4 < 4; ++t4) {
        const u16* src = ((mask9[t4] >> tap) & 1)
            ? (Xbp + (size_t)(prow[t4] + dpos) * CCH + qsw + icb * 64) : zbuf;
        gl2lds16(src, ldsXd[t4]);
      }
#pragma unroll
      for (int t4 = 0; t4 < 4; ++t4) gl2lds16(wsrc[t4] + ko, ldsWd[t4]);
      __syncthreads();
#pragma unroll
      for (int h = 0; h < 2; ++h) {
        short8 af[4], bv[4];
#pragma unroll
        for (int i = 0; i < 4; ++i) af[i] = *(const short8*)(ldsW + aoff[h][i]);
#pragma unroll
        for (int j = 0; j < 4; ++j) bv[j] = *(const short8*)(ldsX + boff[h][j]);
#pragma unroll
        for (int i = 0; i < 4; ++i)
#pragma unroll
          for (int j = 0; j < 4; ++j)
            acc[i][j] = __builtin_amdgcn_mfma_f32_16x16x32_bf16(af[i], bv[j], acc[i][j], 0, 0, 0);
      }
    }
  }

  // epilogue; D[m=(lane>>4)*4+r][n=lane&15]
  const int quad = lane >> 4, col = lane & 15;
  if (MODE == 0) {
    u16* convB = a.outB[tower];
    float s[4] = {0.f, 0.f, 0.f, 0.f}, ss[4] = {0.f, 0.f, 0.f, 0.f};
#pragma unroll
    for (int j = 0; j < 4; ++j) {
      int pl = n0 + wn * 64 + j * 16 + col;
      bool valid = pl < P;
      u16* dst = convB + ((size_t)b * PA_TOTAL + base + pl) * CCH + mt * 128 + wm * 64 + quad * 4;
#pragma unroll
      for (int i = 0; i < 4; ++i) {
        ushort4 hv;
#pragma unroll
        for (int r = 0; r < 4; ++r) {
          u16 hh = f2bf(acc[i][j][r]);
          ((u16*)&hv)[r] = hh;
          float vr = bf2f(hh);                    // accumulate ROUNDED value -> GN self-consistent
          if (valid) { s[i] += vr; ss[i] += vr * vr; }
        }
        if (valid) *(ushort4*)(dst + i * 16) = hv;
      }
    }
#pragma unroll
    for (int i = 0; i < 4; ++i) {
#pragma unroll
      for (int off = 16; off >= 1; off >>= 1) {
        s[i] += __shfl_down(s[i], off, 64);
        ss[i] += __shfl_down(ss[i], off, 64);
      }
    }
    if ((lane & 31) == 0) {
      int half = lane >> 5;
#pragma unroll
      for (int i = 0; i < 4; ++i) {
        float* st = a.stats + tower * 640 +
                    ((size_t)((b * 5 + lvl) * 32 + mt * 16 + wm * 8 + i * 2 + half)) * 2;
        atomicAdd(st, s[i]);
        atomicAdd(st + 1, ss[i]);
      }
    }
  } else {
    float* dout = a.dout;
    if (tower == 0) {
#pragma unroll
      for (int j = 0; j < 4; ++j) {
        int pl = n0 + wn * 64 + j * 16 + col;
        if (pl >= P) continue;
#pragma unroll
        for (int i = 0; i < 4; ++i) {
          int ocb = wm * 64 + i * 16 + quad * 4;
#pragma unroll
          for (int r = 0; r < 4; ++r) {
            int oc = ocb + r;
            float v = acc[i][j][r];
            if (oc < 20)       dout[tb.lb[lvl] + ((size_t)b * 20 + oc) * P + pl] = v + a.biasCls[oc];
            else if (oc == 20) dout[tb.cb[lvl] + (size_t)b * P + pl] = v + a.biasCtr[0];
          }
        }
      }
    } else {
      float sc = a.scales[lvl];
#pragma unroll
      for (int j = 0; j < 4; ++j) {
        int pl = n0 + wn * 64 + j * 16 + col;
        if (pl >= P) continue;
#pragma unroll
        for (int i = 0; i < 4; ++i) {
          int ocb = wm * 64 + i * 16 + quad * 4;
#pragma unroll
          for (int r = 0; r < 4; ++r) {
            int oc = ocb + r;
            if (oc < 4)
              dout[tb.bb[lvl] + ((size_t)b * 4 + oc) * P + pl] = expf((acc[i][j][r] + a.biasBox[oc]) * sc);
          }
        }
      }
    }
  }
}

// ---- GroupNorm pass 2: normalize + affine + ReLU, bf16 -> bf16, coalesced; both towers.
// grid (3424, 2): y = tower
__global__ void gn_norm(const u16* __restrict__ c0, const u16* __restrict__ c1,
                        const float* __restrict__ stats,
                        const float* __restrict__ g0, const float* __restrict__ b0,
                        const float* __restrict__ g1, const float* __restrict__ b1,
                        u16* __restrict__ a0, u16* __restrict__ a1, Tables tb) {
  const int tower = blockIdx.y;
  const u16* convB = tower ? c1 : c0;
  const float* gamma = tower ? g1 : g0;
  const float* beta = tower ? b1 : b0;
  u16* act = tower ? a1 : a0;
  int idx = blockIdx.x * 256 + threadIdx.x;
  int c8 = idx & 31;                 // == group index
  int rest = idx >> 5;
  int p = rest % PA_TOTAL;
  int b = rest / PA_TOTAL;
  int lvl = 0;
#pragma unroll
  for (int i = 1; i < 5; ++i) if (p >= tb.base[i]) lvl = i;
  if (p - tb.base[lvl] >= tb.P[lvl]) return;
  const float* st = stats + tower * 640 + ((size_t)((b * 5 + lvl) * 32 + c8)) * 2;
  float cnt = 8.f * (float)tb.P[lvl];
  float mean = st[0] / cnt;
  float var = st[1] / cnt - mean * mean;
  float inv = rsqrtf(var + 1e-5f);
  const short8 x = *(const short8*)(convB + ((size_t)b * PA_TOTAL + p) * CCH + c8 * 8);
  short8 o;
#pragma unroll
  for (int j = 0; j < 8; ++j) {
    float v = bf2f((u16)x[j]);
    float y = (v - mean) * inv * gamma[c8 * 8 + j] + beta[c8 * 8 + j];
    y = fmaxf(y, 0.f);
    o[j] = (short)f2bf(y);
  }
  *(short8*)(act + ((size_t)b * PA_TOTAL + p) * CCH + c8 * 8) = o;
}

extern "C" void kernel_launch(void* const* d_in, const int* in_sizes, int n_in,
                              void* d_out, int out_size, void* d_ws, size_t ws_size,
                              hipStream_t stream) {
  const float* feat[5];
  for (int i = 0; i < 5; ++i) feat[i] = (const float*)d_in[i];
  const float* cls_tw_w  = (const float*)d_in[5];
  const float* cls_tw_g  = (const float*)d_in[6];
  const float* cls_tw_b  = (const float*)d_in[7];
  const float* box_tw_w  = (const float*)d_in[8];
  const float* box_tw_g  = (const float*)d_in[9];
  const float* box_tw_b  = (const float*)d_in[10];
  const float* cls_pred_w = (const float*)d_in[11];
  const float* cls_pred_b = (const float*)d_in[12];
  const float* box_pred_w = (const float*)d_in[13];
  const float* box_pred_b = (const float*)d_in[14];
  const float* ctr_pred_w = (const float*)d_in[15];
  const float* ctr_pred_b = (const float*)d_in[16];
  const float* scales     = (const float*)d_in[17];
  float* out = (float*)d_out;

  char* ws = (char*)d_ws;
  u16*   zbuf   = (u16*)(ws);                        // 512 B zeros
  float* stats  = (float*)(ws + 512);                // 5120 B: [2 towers][320 groups][2]
  u16*   WrCls  = (u16*)(ws + 8192);                 // 1024 x 2304 bf16
  u16*   WrBox  = (u16*)(ws + 8192 + 4718592);
  u16*   WrPCls = (u16*)(ws + 8192 + 2 * 4718592);   // 128 x 2304 bf16 (21 used)
  u16*   WrPBox = (u16*)(ws + 8192 + 2 * 4718592 + 589824);
  u16*   bufIn   = (u16*)(ws + 10625024);
  u16*   bufAct0 = (u16*)(ws + 10625024 + 1 * (size_t)14024704);
  u16*   bufAct1 = (u16*)(ws + 10625024 + 2 * (size_t)14024704);
  u16*   bufCv0  = (u16*)(ws + 10625024 + 3 * (size_t)14024704);
  u16*   bufCv1  = (u16*)(ws + 10625024 + 4 * (size_t)14024704);

  Tables tb = { {100,50,25,13,7}, {100,50,25,13,7}, {10000,2500,625,169,49},
                {0,10112,12672,13312,13568}, {0,79,99,104,106},
                {0,400000,500000,525000,531760},
                {533720,613720,633720,638720,640072},
                {640464,660464,665464,666714,667052} };

  hipMemsetAsync(zbuf, 0, 512, stream);
  hipMemsetAsync(WrPCls, 0, 589824, stream);
  hipMemsetAsync(WrPBox, 0, 589824, stream);

  reorder_w<<<9216, 256, 0, stream>>>(cls_tw_w, WrCls, 1024 * KTOT);
  reorder_w<<<9216, 256, 0, stream>>>(box_tw_w, WrBox, 1024 * KTOT);
  reorder_pred_cls<<<189, 256, 0, stream>>>(cls_pred_w, ctr_pred_w, WrPCls);
  reorder_w<<<36, 256, 0, stream>>>(box_pred_w, WrPBox, 4 * KTOT);

  FeatPtrs fp = {{feat[0], feat[1], feat[2], feat[3], feat[4]}};
  convert_inputs<<<dim3(PA_TOTAL / 32, 8, 2), 256, 0, stream>>>(fp, bufIn, tb);

  ConvArgs a;
  a.zbuf = zbuf; a.stats = stats; a.dout = out;
  a.biasCls = cls_pred_b; a.biasCtr = ctr_pred_b; a.biasBox = box_pred_b; a.scales = scales;
  a.outB[0] = bufCv0; a.outB[1] = bufCv1;

  for (int s = 0; s < 4; ++s) {
    a.X[0] = (s == 0) ? bufIn : bufAct0;
    a.X[1] = (s == 0) ? bufIn : bufAct1;
    a.Wt[0] = WrCls + (size_t)s * 256 * KTOT;
    a.Wt[1] = WrBox + (size_t)s * 256 * KTOT;
    hipMemsetAsync(stats, 0, 5120, stream);
    conv_mfma<0><<<dim3(107, 2, 4), 256, 0, stream>>>(a, tb);
    gn_norm<<<dim3(3424, 2), 256, 0, stream>>>(bufCv0, bufCv1, stats,
                                               cls_tw_g + s * 256, cls_tw_b + s * 256,
                                               box_tw_g + s * 256, box_tw_b + s * 256,
                                               bufAct0, bufAct1, tb);
  }
  a.X[0] = bufAct0; a.X[1] = bufAct1;
  a.Wt[0] = WrPCls; a.Wt[1] = WrPBox;
  conv_mfma<1><<<dim3(108, 2, 2), 256, 0, stream>>>(a, tb);
}